// Round 1
// baseline (447.134 us; speedup 1.0000x reference)
//
#include <hip/hip_runtime.h>

#define NN 50000
#define NE 800000
#define KF 256
#define MF 64

#define NBK 782      // node buckets of 64: ceil(50000/64)
#define HB 49        // scatter blocks
#define EPB 16384    // edges per scatter block (49*16384 >= 800000)
#define CAP 1536     // fixed slots per bucket (mean 1024 + ~16 sigma)
#define GEMMB 196    // gemm blocks: each does 256 rows
#define OVF_CAP 4096 // overflow list capacity (never used in practice)

typedef __attribute__((ext_vector_type(8))) short short8;
typedef __attribute__((ext_vector_type(4))) float f32x4;

static __device__ __forceinline__ unsigned short f2bf(float x) {
  unsigned int u = __float_as_uint(x);
  u += 0x7FFF + ((u >> 16) & 1);  // round-nearest-even
  return (unsigned short)(u >> 16);
}
static __device__ __forceinline__ float bf2f(unsigned short u) {
  return __uint_as_float(((unsigned int)u) << 16);
}

// ---- Kernel 1: fused edge scatter (blocks 0..HB-1) + MFMA GEMM (HB..) ----
// Scatter: per-block LDS histogram -> one global atomicAdd per touched bucket
// reserves a chunk in that bucket's fixed-stride region (no separate hist
// kernel, no prefix scans). GEMM: unchanged math; W prepacked into LDS
// per-block (W is 64KB, L2-resident), removing the prepack dispatch.
__global__ __launch_bounds__(1024, 4) void scatter_gemm(
    const int* __restrict__ src, const int* __restrict__ dst,
    int* __restrict__ gCur, int* __restrict__ gOvf,
    unsigned int* __restrict__ ovf, int* __restrict__ eidx,
    const float* __restrict__ h, const float* __restrict__ W,
    const float* __restrict__ norm, unsigned short* __restrict__ hwb) {
  const int t = threadIdx.x;

  if (blockIdx.x >= HB) {  // ---- GEMM branch: 4 x 64-row tiles ----
    __shared__ unsigned short wt[16384];  // 32 KB B-fragment table
    // prepack W -> LDS (same layout as before: f = k0i*256 + nt*64 + quad*16 + m)
    for (int f = t; f < 2048; f += 1024) {
      const int m = f & 15;
      const int quad = (f >> 4) & 3;
      const int nt = (f >> 6) & 3;
      const int k0i = f >> 8;
      const int n = nt * 16 + m;
      const int kb = k0i * 32 + quad * 8;
      short8 p;
#pragma unroll
      for (int j = 0; j < 8; ++j) p[j] = (short)f2bf(W[(kb + j) * MF + n]);
      *(short8*)(wt + (size_t)f * 8) = p;
    }

    const int sub = t >> 8;        // 0..3
    const int tt = t & 255;
    const int lane = tt & 63;
    const int wv = tt >> 6;        // 0..3
    const int m = lane & 15;
    const int quad = lane >> 4;    // 0..3
    const int row0 = (blockIdx.x - HB) * 256 + sub * 64;
    const int arow = row0 + wv * 16 + m;
    const int rowc = (arow < NN) ? arow : (NN - 1);  // clamp; store guarded
    const float4* ap = (const float4*)(h + (size_t)rowc * KF + quad * 8);

    float4 a[16];
#pragma unroll
    for (int k = 0; k < 8; ++k) {
      a[2 * k] = ap[k * 8];
      a[2 * k + 1] = ap[k * 8 + 1];
    }
    __builtin_amdgcn_sched_barrier(0);  // all 16 A-loads issue first

    short8 af[8];
#pragma unroll
    for (int k = 0; k < 8; ++k) {
      const float4 a0 = a[2 * k];
      const float4 a1 = a[2 * k + 1];
      af[k][0] = (short)f2bf(a0.x); af[k][1] = (short)f2bf(a0.y);
      af[k][2] = (short)f2bf(a0.z); af[k][3] = (short)f2bf(a0.w);
      af[k][4] = (short)f2bf(a1.x); af[k][5] = (short)f2bf(a1.y);
      af[k][6] = (short)f2bf(a1.z); af[k][7] = (short)f2bf(a1.w);
    }
    __builtin_amdgcn_sched_barrier(0);
    __syncthreads();  // wt ready

    f32x4 acc[4];
#pragma unroll
    for (int i = 0; i < 4; ++i) acc[i] = (f32x4){0.f, 0.f, 0.f, 0.f};

    const short8* wp = (const short8*)wt;
#pragma unroll
    for (int k0i = 0; k0i < 8; ++k0i) {
      const short8* wk = wp + k0i * 256 + lane;
#pragma unroll
      for (int nt = 0; nt < 4; ++nt) {
        const short8 bf = wk[nt * 64];  // ds_read_b128, conflict-free
        acc[nt] = __builtin_amdgcn_mfma_f32_16x16x32_bf16(af[k0i], bf, acc[nt], 0, 0, 0);
      }
    }

    const int gm0 = row0 + wv * 16 + quad * 4;
    float nrm[4];
#pragma unroll
    for (int r = 0; r < 4; ++r) nrm[r] = (gm0 + r < NN) ? norm[gm0 + r] : 0.f;
#pragma unroll
    for (int nt = 0; nt < 4; ++nt) {
#pragma unroll
      for (int r = 0; r < 4; ++r) {
        const int gm = gm0 + r;
        if (gm < NN) hwb[(size_t)gm * MF + nt * 16 + m] = f2bf(acc[nt][r] * nrm[r]);
      }
    }
    return;
  }

  // ---- scatter branch: one read of src/dst, edges held in 16 VGPRs ----
  __shared__ int hh[NBK];  // local histogram
  __shared__ int bb[NBK];  // reserved base -> running cursor
  const int base = (int)blockIdx.x * EPB;
  unsigned int ev[EPB / 1024];
#pragma unroll
  for (int i = 0; i < EPB / 1024; ++i) {
    const int e = base + i * 1024 + t;
    ev[i] = (e < NE) ? (((unsigned)src[e] << 16) | (unsigned)dst[e])
                     : 0xFFFFFFFFu;  // sentinel (d=0xFFFF impossible: d<50000)
  }
  for (int i = t; i < NBK; i += 1024) hh[i] = 0;
  __syncthreads();
#pragma unroll
  for (int i = 0; i < EPB / 1024; ++i)
    if (ev[i] != 0xFFFFFFFFu) atomicAdd(&hh[(ev[i] & 0xFFFFu) >> 6], 1);
  __syncthreads();
  for (int i = t; i < NBK; i += 1024) {
    const int c = hh[i];
    bb[i] = c ? atomicAdd(&gCur[i], c) : 0;  // chunk reservation
  }
  __syncthreads();
#pragma unroll
  for (int i = 0; i < EPB / 1024; ++i) {
    const unsigned v = ev[i];
    if (v != 0xFFFFFFFFu) {
      const int d = (int)(v & 0xFFFFu);
      const int bk = d >> 6;
      const int p = atomicAdd(&bb[bk], 1);
      if (p < CAP) {
        eidx[(size_t)bk * CAP + p] = (int)((v >> 16) << 6) | (d & 63);
      } else {  // statistically unreachable; kept for correctness
        const int o = atomicAdd(gOvf, 1);
        if (o < OVF_CAP) ovf[o] = v;
      }
    }
  }
}

// ---- Kernel 2: gather + LDS fp32 atomic-panel accumulate + epilogue ----
// No histogram, no scan, no counting sort: each wave streams 16 edges/iter
// (16 hwb row-loads of 128B in flight), ds_add_f32 into a 64x64 panel.
// Panel adds are bank-conflict-free (64 lanes -> 32 banks 2-way).
__global__ __launch_bounds__(1024, 4) void gather_acc(
    const int* __restrict__ gCur, const int* __restrict__ gOvf,
    const unsigned int* __restrict__ ovf, const int* __restrict__ eidx,
    const unsigned short* __restrict__ hwb, const float* __restrict__ norm,
    const float* __restrict__ bias, float* __restrict__ out) {
  __shared__ float acc[4096];  // 64 nodes x 64 feats, 16 KB
  const int t = threadIdx.x;
  const int g = blockIdx.x;
  ((f32x4*)acc)[t] = (f32x4){0.f, 0.f, 0.f, 0.f};
  int cnt = gCur[g];
  cnt = (cnt < CAP) ? cnt : CAP;
  cnt = __builtin_amdgcn_readfirstlane(cnt);
  const int lane = t & 63;
  const int wv = __builtin_amdgcn_readfirstlane(t >> 6);  // 0..15, uniform
  __syncthreads();

  const int chunk = (cnt + 15) >> 4;  // per-wave contiguous chunk
  const int i0 = wv * chunk;
  const int iend = ((i0 + chunk) < cnt) ? (i0 + chunk) : cnt;
  const int* ep = eidx + (size_t)g * CAP;
  int i = i0;
  int vv[16];
  float xx[16];
  for (; i + 16 <= iend; i += 16) {
#pragma unroll
    for (int j = 0; j < 16; ++j) vv[j] = ep[i + j];  // wave-uniform -> s_load
#pragma unroll
    for (int j = 0; j < 16; ++j)
      xx[j] = bf2f(hwb[(size_t)(vv[j] >> 6) * MF + lane]);  // 16 x 128B in flight
    __builtin_amdgcn_sched_barrier(0);
#pragma unroll
    for (int j = 0; j < 16; ++j)
      atomicAdd(&acc[((vv[j] & 63) << 6) + lane], xx[j]);  // ds_add_f32
  }
  for (; i < iend; ++i) {
    const int v = ep[i];
    const float x = bf2f(hwb[(size_t)(v >> 6) * MF + lane]);
    atomicAdd(&acc[((v & 63) << 6) + lane], x);
  }

  const int no = *gOvf;  // always 0 in practice; one uniform load
  if (no > 0) {
    const int nn = (no < OVF_CAP) ? no : OVF_CAP;
    for (int ii = wv; ii < nn; ii += 16) {
      const unsigned v = ovf[ii];
      const int d = (int)(v & 0xFFFFu);
      if ((d >> 6) == g) {
        const float x = bf2f(hwb[(size_t)(v >> 16) * MF + lane]);
        atomicAdd(&acc[((d & 63) << 6) + lane], x);
      }
    }
  }
  __syncthreads();

  const float bi = bias[lane];
#pragma unroll
  for (int n = wv; n < 64; n += 16) {
    const int vtx = (g << 6) + n;
    if (vtx < NN) {
      const float o = acc[(n << 6) + lane] * norm[vtx] + bi;
      out[(size_t)vtx * MF + lane] = fmaxf(o, 0.f);
    }
  }
}

extern "C" void kernel_launch(void* const* d_in, const int* in_sizes, int n_in,
                              void* d_out, int out_size, void* d_ws, size_t ws_size,
                              hipStream_t stream) {
  const float* h = (const float*)d_in[0];
  const float* norm = (const float*)d_in[1];
  const float* W = (const float*)d_in[2];
  const float* bias = (const float*)d_in[3];
  const int* src = (const int*)d_in[4];
  const int* dst = (const int*)d_in[5];
  float* out = (float*)d_out;

  unsigned short* hwb = (unsigned short*)d_ws;            // NN*MF bf16 (6.4 MB)
  int* gCur = (int*)(hwb + (size_t)NN * MF);              // NBK bucket cursors
  int* gOvf = gCur + NBK;                                 // overflow counter
  unsigned int* ovf = (unsigned int*)(gOvf + 1);          // OVF_CAP entries
  int* eidx = (int*)(ovf + OVF_CAP);                      // NBK*CAP (4.8 MB)
  const size_t need = (size_t)NN * MF * 2 +
                      ((size_t)NBK + 1 + OVF_CAP + (size_t)NBK * CAP) * 4;
  if (ws_size < need) return;

  hipMemsetAsync(gCur, 0, (NBK + 1) * sizeof(int), stream);  // 3 KB
  scatter_gemm<<<HB + GEMMB, 1024, 0, stream>>>(src, dst, gCur, gOvf, ovf,
                                                eidx, h, W, norm, hwb);
  gather_acc<<<NBK, 1024, 0, stream>>>(gCur, gOvf, ovf, eidx, hwb, norm, bias,
                                       out);
}

// Round 2
// 134.707 us; speedup vs baseline: 3.3193x; 3.3193x over previous
//
#include <hip/hip_runtime.h>

#define NN 50000
#define NE 800000
#define KF 256
#define MF 64

#define NBK 782      // node buckets of 64: ceil(50000/64)
#define HB 49        // scatter blocks
#define EPB 16384    // edges per scatter block (49*16384 >= 800000)
#define CAP 1536     // fixed slots per bucket (mean 1024 + ~16 sigma)
#define GEMMB 196    // gemm blocks: each does 256 rows
#define OVF_CAP 4096 // overflow list capacity (never used in practice)

typedef __attribute__((ext_vector_type(8))) short short8;
typedef __attribute__((ext_vector_type(4))) float f32x4;

static __device__ __forceinline__ unsigned short f2bf(float x) {
  unsigned int u = __float_as_uint(x);
  u += 0x7FFF + ((u >> 16) & 1);  // round-nearest-even
  return (unsigned short)(u >> 16);
}
static __device__ __forceinline__ float bf2f(unsigned short u) {
  return __uint_as_float(((unsigned int)u) << 16);
}

// ---- Kernel 1: fused edge scatter (blocks 0..HB-1) + MFMA GEMM (HB..) ----
// Scatter: per-block LDS histogram -> one global atomicAdd per touched bucket
// reserves a chunk in that bucket's fixed-stride region. GEMM: W prepacked
// into LDS per-block. No launch_bounds min-waves: grid (245) <= 256 CUs, so
// 1 block/CU is free and the A-load burst gets its 64+ result VGPRs.
__global__ __launch_bounds__(1024) void scatter_gemm(
    const int* __restrict__ src, const int* __restrict__ dst,
    int* __restrict__ gCur, int* __restrict__ gOvf,
    unsigned int* __restrict__ ovf, int* __restrict__ eidx,
    const float* __restrict__ h, const float* __restrict__ W,
    const float* __restrict__ norm, unsigned short* __restrict__ hwb) {
  const int t = threadIdx.x;

  if (blockIdx.x >= HB) {  // ---- GEMM branch: 4 x 64-row tiles ----
    __shared__ unsigned short wt[16384];  // 32 KB B-fragment table
    // prepack W -> LDS (layout: f = k0i*256 + nt*64 + quad*16 + m)
    for (int f = t; f < 2048; f += 1024) {
      const int m = f & 15;
      const int quad = (f >> 4) & 3;
      const int nt = (f >> 6) & 3;
      const int k0i = f >> 8;
      const int n = nt * 16 + m;
      const int kb = k0i * 32 + quad * 8;
      short8 p;
#pragma unroll
      for (int j = 0; j < 8; ++j) p[j] = (short)f2bf(W[(kb + j) * MF + n]);
      *(short8*)(wt + (size_t)f * 8) = p;
    }

    const int sub = t >> 8;        // 0..3
    const int tt = t & 255;
    const int lane = tt & 63;
    const int wv = tt >> 6;        // 0..3
    const int m = lane & 15;
    const int quad = lane >> 4;    // 0..3
    const int row0 = (blockIdx.x - HB) * 256 + sub * 64;
    const int arow = row0 + wv * 16 + m;
    const int rowc = (arow < NN) ? arow : (NN - 1);  // clamp; store guarded
    const float4* ap = (const float4*)(h + (size_t)rowc * KF + quad * 8);

    float4 a[16];
#pragma unroll
    for (int k = 0; k < 8; ++k) {
      a[2 * k] = ap[k * 8];
      a[2 * k + 1] = ap[k * 8 + 1];
    }
    __builtin_amdgcn_sched_barrier(0);  // all 16 A-loads issue first

    short8 af[8];
#pragma unroll
    for (int k = 0; k < 8; ++k) {
      const float4 a0 = a[2 * k];
      const float4 a1 = a[2 * k + 1];
      af[k][0] = (short)f2bf(a0.x); af[k][1] = (short)f2bf(a0.y);
      af[k][2] = (short)f2bf(a0.z); af[k][3] = (short)f2bf(a0.w);
      af[k][4] = (short)f2bf(a1.x); af[k][5] = (short)f2bf(a1.y);
      af[k][6] = (short)f2bf(a1.z); af[k][7] = (short)f2bf(a1.w);
    }
    __syncthreads();  // wt ready

    f32x4 acc[4];
#pragma unroll
    for (int i = 0; i < 4; ++i) acc[i] = (f32x4){0.f, 0.f, 0.f, 0.f};

    const short8* wp = (const short8*)wt;
#pragma unroll
    for (int k0i = 0; k0i < 8; ++k0i) {
      const short8* wk = wp + k0i * 256 + lane;
#pragma unroll
      for (int nt = 0; nt < 4; ++nt) {
        const short8 bf = wk[nt * 64];  // ds_read_b128, conflict-free
        acc[nt] = __builtin_amdgcn_mfma_f32_16x16x32_bf16(af[k0i], bf, acc[nt], 0, 0, 0);
      }
    }

    const int gm0 = row0 + wv * 16 + quad * 4;
    float nrm[4];
#pragma unroll
    for (int r = 0; r < 4; ++r) nrm[r] = (gm0 + r < NN) ? norm[gm0 + r] : 0.f;
#pragma unroll
    for (int nt = 0; nt < 4; ++nt) {
#pragma unroll
      for (int r = 0; r < 4; ++r) {
        const int gm = gm0 + r;
        if (gm < NN) hwb[(size_t)gm * MF + nt * 16 + m] = f2bf(acc[nt][r] * nrm[r]);
      }
    }
    return;
  }

  // ---- scatter branch: one read of src/dst, edges held in 16 VGPRs ----
  __shared__ int hh[NBK];  // local histogram
  __shared__ int bb[NBK];  // reserved base -> running cursor
  const int base = (int)blockIdx.x * EPB;
  unsigned int ev[EPB / 1024];
#pragma unroll
  for (int i = 0; i < EPB / 1024; ++i) {
    const int e = base + i * 1024 + t;
    ev[i] = (e < NE) ? (((unsigned)src[e] << 16) | (unsigned)dst[e])
                     : 0xFFFFFFFFu;  // sentinel (dst=0xFFFF impossible: d<50000)
  }
  for (int i = t; i < NBK; i += 1024) hh[i] = 0;
  __syncthreads();
#pragma unroll
  for (int i = 0; i < EPB / 1024; ++i)
    if (ev[i] != 0xFFFFFFFFu) atomicAdd(&hh[(ev[i] & 0xFFFFu) >> 6], 1);
  __syncthreads();
  for (int i = t; i < NBK; i += 1024) {
    const int c = hh[i];
    bb[i] = c ? atomicAdd(&gCur[i], c) : 0;  // chunk reservation
  }
  __syncthreads();
#pragma unroll
  for (int i = 0; i < EPB / 1024; ++i) {
    const unsigned v = ev[i];
    if (v != 0xFFFFFFFFu) {
      const int d = (int)(v & 0xFFFFu);
      const int bk = d >> 6;
      const int p = atomicAdd(&bb[bk], 1);
      if (p < CAP) {
        eidx[(size_t)bk * CAP + p] = (int)((v >> 16) << 6) | (d & 63);
      } else {  // statistically unreachable; kept for correctness
        const int o = atomicAdd(gOvf, 1);
        if (o < OVF_CAP) ovf[o] = v;
      }
    }
  }
}

// ---- Kernel 2: per-bucket counting sort (LDS, int atomics) + gather ----
// Proven structure (round-0 40us class): sort the bucket's edges by local
// node, then each wave register-accumulates 4 nodes with 8 row-loads in
// flight. eidx read exactly once (edge words stashed in regs during hist).
__global__ __launch_bounds__(1024) void sort_gather(
    const int* __restrict__ gCur, const int* __restrict__ gOvf,
    const unsigned int* __restrict__ ovf, const int* __restrict__ eidx,
    const unsigned short* __restrict__ hwb, const float* __restrict__ norm,
    const float* __restrict__ bias, float* __restrict__ out) {
  __shared__ int hcnt[64];   // histogram -> node end (after scan)
  __shared__ int sBeg[64];   // node start (local)
  __shared__ int sCur[64];
  __shared__ int sE[CAP];
  const int t = threadIdx.x;
  const int g = blockIdx.x;
  int cnt = gCur[g];
  cnt = (cnt < CAP) ? cnt : CAP;  // excess (never happens) is in ovf list
  cnt = __builtin_amdgcn_readfirstlane(cnt);
  const int* ep = eidx + (size_t)g * CAP;
  if (t < 64) hcnt[t] = 0;
  __syncthreads();
  // hist pass; stash edge words in regs (cnt <= 1536 -> <= 2 per thread)
  int v0 = -1, v1 = -1;
  if (t < cnt) {
    v0 = ep[t];
    atomicAdd(&hcnt[v0 & 63], 1);
  }
  if (t + 1024 < cnt) {
    v1 = ep[t + 1024];
    atomicAdd(&hcnt[v1 & 63], 1);
  }
  __syncthreads();
  if (t < 64) {  // wave 0: exclusive scan of 64 counts
    const int v = hcnt[t];
    int incl = v;
#pragma unroll
    for (int off = 1; off < 64; off <<= 1) {
      const int u = __shfl_up(incl, off, 64);
      if (t >= off) incl += u;
    }
    sBeg[t] = incl - v;
    sCur[t] = incl - v;
    hcnt[t] = incl;  // end
  }
  __syncthreads();
  if (v0 >= 0) sE[atomicAdd(&sCur[v0 & 63], 1)] = v0 >> 6;
  if (v1 >= 0) sE[atomicAdd(&sCur[v1 & 63], 1)] = v1 >> 6;
  __syncthreads();

  const int lane = t & 63;
  const int wv = t >> 6;  // 0..15; wave handles nodes wv, wv+16, wv+32, wv+48
  const float bi = bias[lane];
  const int novf = __builtin_amdgcn_readfirstlane(*gOvf);  // 0 in practice
#pragma unroll
  for (int nl = wv; nl < 64; nl += 16) {
    const int vtx = (g << 6) + nl;
    if (vtx >= NN) continue;
    const int s0i = __builtin_amdgcn_readfirstlane(sBeg[nl]);
    const int e0i = __builtin_amdgcn_readfirstlane(hcnt[nl]);
    float acc = 0.f;
    int i = s0i;
    for (; i + 8 <= e0i; i += 8) {  // 8 row-loads in flight
      const int s0 = sE[i], s1 = sE[i + 1], s2 = sE[i + 2], s3 = sE[i + 3];
      const int s4 = sE[i + 4], s5 = sE[i + 5], s6 = sE[i + 6], s7 = sE[i + 7];
      const unsigned short x0 = hwb[(size_t)s0 * MF + lane];
      const unsigned short x1 = hwb[(size_t)s1 * MF + lane];
      const unsigned short x2 = hwb[(size_t)s2 * MF + lane];
      const unsigned short x3 = hwb[(size_t)s3 * MF + lane];
      const unsigned short x4 = hwb[(size_t)s4 * MF + lane];
      const unsigned short x5 = hwb[(size_t)s5 * MF + lane];
      const unsigned short x6 = hwb[(size_t)s6 * MF + lane];
      const unsigned short x7 = hwb[(size_t)s7 * MF + lane];
      acc += bf2f(x0); acc += bf2f(x1); acc += bf2f(x2); acc += bf2f(x3);
      acc += bf2f(x4); acc += bf2f(x5); acc += bf2f(x6); acc += bf2f(x7);
    }
    for (; i < e0i; ++i) acc += bf2f(hwb[(size_t)sE[i] * MF + lane]);
    if (novf > 0) {  // cold path, wave-uniform skip
      const int nn = (novf < OVF_CAP) ? novf : OVF_CAP;
      for (int ii = 0; ii < nn; ++ii) {
        const unsigned v = ovf[ii];
        if ((int)(v & 0xFFFFu) == vtx)
          acc += bf2f(hwb[(size_t)(v >> 16) * MF + lane]);
      }
    }
    const float o = acc * norm[vtx] + bi;
    out[(size_t)vtx * MF + lane] = fmaxf(o, 0.f);
  }
}

extern "C" void kernel_launch(void* const* d_in, const int* in_sizes, int n_in,
                              void* d_out, int out_size, void* d_ws, size_t ws_size,
                              hipStream_t stream) {
  const float* h = (const float*)d_in[0];
  const float* norm = (const float*)d_in[1];
  const float* W = (const float*)d_in[2];
  const float* bias = (const float*)d_in[3];
  const int* src = (const int*)d_in[4];
  const int* dst = (const int*)d_in[5];
  float* out = (float*)d_out;

  unsigned short* hwb = (unsigned short*)d_ws;            // NN*MF bf16 (6.4 MB)
  int* gCur = (int*)(hwb + (size_t)NN * MF);              // NBK bucket cursors
  int* gOvf = gCur + NBK;                                 // overflow counter
  unsigned int* ovf = (unsigned int*)(gOvf + 1);          // OVF_CAP entries
  int* eidx = (int*)(ovf + OVF_CAP);                      // NBK*CAP (4.8 MB)
  const size_t need = (size_t)NN * MF * 2 +
                      ((size_t)NBK + 1 + OVF_CAP + (size_t)NBK * CAP) * 4;
  if (ws_size < need) return;

  hipMemsetAsync(gCur, 0, (NBK + 1) * sizeof(int), stream);  // 3 KB
  scatter_gemm<<<HB + GEMMB, 1024, 0, stream>>>(src, dst, gCur, gOvf, ovf,
                                                eidx, h, W, norm, hwb);
  sort_gather<<<NBK, 1024, 0, stream>>>(gCur, gOvf, ovf, eidx, hwb, norm, bias,
                                        out);
}